// Round 2
// baseline (230.555 us; speedup 1.0000x reference)
//
#include <hip/hip_runtime.h>
#include <hip/hip_cooperative_groups.h>
#include <math.h>

#define NI 256
#define NO 256
#define BATCH 1024

namespace cg = cooperative_groups;

// Closed form (derived from the KKT system's block structure):
//   M = lhs lhs^T = [[NO*I, B],[B^T, 2I]] with 1^T B = 0  (each equal-edge
//   pair's +1/-1 cancels in the column sum), so
//   1^T lambda_1 = (sum_i xs[b,i] - sum_e softplus(param_e)) / NO
// and the per-output equal-edge multiplier contributes 0 to the output sum:
//   out[b,o] = C_o + (Sx_b - total) / NO,  C_o = sum_j softplus(param[o*NI+j])
// Verified vs reference in R1 (absmax 0.125 on ~2e2-magnitude outputs).

__device__ __forceinline__ float softplus_f(float x) {
    // log(1+exp(x)), numerically stable
    return fmaxf(x, 0.0f) + log1pf(expf(-fabsf(x)));
}

__device__ __forceinline__ float block_reduce_256(float v, float* lds) {
    // 256 threads = 4 waves of 64
    #pragma unroll
    for (int off = 32; off > 0; off >>= 1)
        v += __shfl_down(v, off, 64);
    const int lane = threadIdx.x & 63;
    const int wave = threadIdx.x >> 6;
    if (lane == 0) lds[wave] = v;
    __syncthreads();
    float t = 0.0f;
    if (threadIdx.x < 4) t = lds[threadIdx.x];
    t += __shfl_down(t, 2, 64);
    t += __shfl_down(t, 1, 64);
    if (threadIdx.x == 0) lds[0] = t;
    __syncthreads();
    return lds[0];
}

// Single cooperative kernel, grid = BATCH blocks x 256 threads (4 blocks/CU).
// Phase 1: blocks 0..NO-1 compute ws[o] = C_o; all blocks compute
//          ws[NO + b] = Sx_b. grid.sync(). Phase 2: block b writes row b.
__global__ __launch_bounds__(256, 4) void fused_kernel(const float* __restrict__ xs,
                                                       const float* __restrict__ param,
                                                       float* __restrict__ out,
                                                       float* __restrict__ ws) {
    __shared__ float lds[4];
    const int b = blockIdx.x;
    const int tid = threadIdx.x;

    if (b < NO) {  // block-uniform branch; barriers inside are safe
        const float c = softplus_f(param[b * NI + tid]);
        const float s = block_reduce_256(c, lds);
        if (tid == 0) ws[b] = s;
        __syncthreads();  // lds reuse guard
    }
    {
        const float x = xs[b * NI + tid];
        const float s = block_reduce_256(x, lds);
        if (tid == 0) ws[NO + b] = s;
    }

    cg::this_grid().sync();

    const float Co = ws[tid];
    const float total = block_reduce_256(Co, lds);  // 256 L2-resident loads/block
    const float Sx = ws[NO + b];
    out[b * NO + tid] = Co + (Sx - total) * (1.0f / (float)NO);
}

extern "C" void kernel_launch(void* const* d_in, const int* in_sizes, int n_in,
                              void* d_out, int out_size, void* d_ws, size_t ws_size,
                              hipStream_t stream) {
    const float* xs    = (const float*)d_in[0];   // [BATCH, NI]
    const float* param = (const float*)d_in[1];   // [NO*NI]
    // d_in[2] (lhs) unused: its structure is folded into the closed form.
    float* out = (float*)d_out;                   // [BATCH, NO]
    float* ws  = (float*)d_ws;                    // NO + BATCH floats

    void* args[] = { (void*)&xs, (void*)&param, (void*)&out, (void*)&ws };
    hipLaunchCooperativeKernel((void*)fused_kernel, dim3(BATCH), dim3(256),
                               args, 0, stream);
}

// Round 3
// 164.437 us; speedup vs baseline: 1.4021x; 1.4021x over previous
//
#include <hip/hip_runtime.h>
#include <math.h>

#define NI 256
#define NO 256
#define BATCH 1024

// Closed form (derived from the KKT system's block structure):
//   M = lhs lhs^T = [[NO*I, B],[B^T, 2I]] with 1^T B = 0, so
//   1^T lambda_1 = (sum_i xs[b,i] - sum_e softplus(param_e)) / NO
// and the per-output equal-edge multiplier cancels in the output sum:
//   out[b,o] = C_o + (Sx_b - total) / NO,  C_o = sum_j softplus(param[o*NI+j])
// Verified vs reference in R1 (absmax 0.125, threshold 0.57).
// R2 lesson: cooperative launch + grid.sync costs +66us in graph replay — the
// two-kernel split is the right structure. 96% of dur_us is the harness's
// 2x512MB d_ws poison fills (~158us at ~6.8TB/s); only ~6us is ours.

__device__ __forceinline__ float softplus_f(float x) {
    return fmaxf(x, 0.0f) + log1pf(expf(-fabsf(x)));
}

__device__ __forceinline__ float wave_reduce_64(float v) {
    #pragma unroll
    for (int off = 32; off > 0; off >>= 1)
        v += __shfl_down(v, off, 64);
    return v;
}

// grid = (NO + BATCH)/4 = 320 blocks x 256 threads; one wave per 256-elem row.
// Rows [0, NO):          ws[o]      = C_o = sum_j softplus(param[o*NI+j])
// Rows [NO, NO+BATCH):   ws[NO + b] = Sx_b = sum_i xs[b*NI+i]
__global__ __launch_bounds__(256) void reduce_kernel(const float* __restrict__ xs,
                                                     const float* __restrict__ param,
                                                     float* __restrict__ ws) {
    const int lane = threadIdx.x & 63;
    const int row = blockIdx.x * 4 + (threadIdx.x >> 6);
    float s;
    if (row < NO) {
        const float4 p = ((const float4*)(param + row * NI))[lane];
        s = softplus_f(p.x) + softplus_f(p.y) + softplus_f(p.z) + softplus_f(p.w);
    } else {
        const float4 x = ((const float4*)(xs + (row - NO) * NI))[lane];
        s = (x.x + x.y) + (x.z + x.w);
    }
    s = wave_reduce_64(s);
    if (lane == 0) ws[row] = s;
}

// grid = BATCH/4 = 256 blocks x 256 threads. Thread o holds Co in a register;
// block reduces total once, then writes 4 output rows.
__global__ __launch_bounds__(256) void out_kernel(const float* __restrict__ ws,
                                                  float* __restrict__ out) {
    __shared__ float lds[4];
    const int o = threadIdx.x;
    const float Co = ws[o];

    // block-reduce the 256 Co values (L2-resident) to get total
    float t = wave_reduce_64(Co);
    const int lane = o & 63;
    const int wave = o >> 6;
    if (lane == 0) lds[wave] = t;
    __syncthreads();
    const float total = lds[0] + lds[1] + lds[2] + lds[3];

    const int b0 = blockIdx.x * 4;
    #pragma unroll
    for (int r = 0; r < 4; ++r) {
        const float Sx = ws[NO + b0 + r];
        out[(b0 + r) * NO + o] = Co + (Sx - total) * (1.0f / (float)NO);
    }
}

extern "C" void kernel_launch(void* const* d_in, const int* in_sizes, int n_in,
                              void* d_out, int out_size, void* d_ws, size_t ws_size,
                              hipStream_t stream) {
    const float* xs    = (const float*)d_in[0];   // [BATCH, NI]
    const float* param = (const float*)d_in[1];   // [NO*NI]
    // d_in[2] (lhs) unused: its structure is folded into the closed form.
    float* out = (float*)d_out;                   // [BATCH, NO]
    float* ws  = (float*)d_ws;                    // NO + BATCH floats

    reduce_kernel<<<(NO + BATCH) / 4, 256, 0, stream>>>(xs, param, ws);
    out_kernel<<<BATCH / 4, 256, 0, stream>>>(ws, out);
}